// Round 5
// baseline (68.318 us; speedup 1.0000x reference)
//
#include <hip/hip_runtime.h>
#include <math.h>

// B=8, N=1024, D=256, C=8192
#define QROWS 8192
#define DDIM  256
#define CCNT  8192
#define BM    256
#define BN    256
#define BK    32
#define CBLKS (CCNT / BN)    // 32

typedef __attribute__((ext_vector_type(4))) float f32x4;
typedef __attribute__((ext_vector_type(8))) short bf16x8;

__device__ __forceinline__ unsigned short f2bf(float f) {
    unsigned u = __float_as_uint(f);
    u += 0x7fffu + ((u >> 16) & 1u);          // round-to-nearest-even
    return (unsigned short)(u >> 16);
}
__device__ __forceinline__ unsigned u32max(unsigned a, unsigned b) { return a > b ? a : b; }
__device__ __forceinline__ unsigned u32min(unsigned a, unsigned b) { return a < b ? a : b; }

// u32 key: 24-bit monotone float + 8-bit (255 - local_col); bigger = better, lower col wins ties
__device__ __forceinline__ unsigned key32(float v, unsigned enc) {
    unsigned u = __float_as_uint(v);
    unsigned s = (unsigned)((int)u >> 31);
    return ((u ^ (s | 0x80000000u)) & 0xFFFFFF00u) | enc;
}

// ---------- merged prep: x -> bf16 ; e -> l2-normalized bf16 ----------
__global__ void k_prep(const float* __restrict__ x, unsigned short* __restrict__ xb,
                       const float* __restrict__ e, unsigned short* __restrict__ eb) {
    const int bid = blockIdx.x;
    if (bid < 1024) {                         // x: 1024 blocks, 8 el/thread
        const int i = (bid * 256 + threadIdx.x) * 8;
        const float4 f0 = *reinterpret_cast<const float4*>(x + i);
        const float4 f1 = *reinterpret_cast<const float4*>(x + i + 4);
        uint4 o;
        o.x = f2bf(f0.x) | ((unsigned)f2bf(f0.y) << 16);
        o.y = f2bf(f0.z) | ((unsigned)f2bf(f0.w) << 16);
        o.z = f2bf(f1.x) | ((unsigned)f2bf(f1.y) << 16);
        o.w = f2bf(f1.z) | ((unsigned)f2bf(f1.w) << 16);
        *reinterpret_cast<uint4*>(xb + i) = o;
    } else {                                  // e: 2048 blocks, 4 rows/block
        const int row  = (bid - 1024) * 4 + (threadIdx.x >> 6);
        const int lane = threadIdx.x & 63;
        const float4 v = *reinterpret_cast<const float4*>(e + (size_t)row * DDIM + lane * 4);
        float s = v.x * v.x + v.y * v.y + v.z * v.z + v.w * v.w;
        #pragma unroll
        for (int off = 1; off < 64; off <<= 1) s += __shfl_xor(s, off);
        const float inv = 1.0f / fmaxf(sqrtf(s), 1e-12f);
        ushort4 o;
        o.x = f2bf(v.x * inv); o.y = f2bf(v.y * inv);
        o.z = f2bf(v.z * inv); o.w = f2bf(v.w * inv);
        *reinterpret_cast<ushort4*>(eb + (size_t)row * DDIM + lane * 4) = o;
    }
}

#define GLOAD_LDS(g, s) \
    __builtin_amdgcn_global_load_lds((const __attribute__((address_space(1))) void*)(g), \
                                     (__attribute__((address_space(3))) void*)(s), 16, 0, 0)

#define SBAR do { asm volatile("" ::: "memory"); __builtin_amdgcn_s_barrier(); \
                  asm volatile("" ::: "memory"); } while (0)
#define WAIT_LGKM0 do { asm volatile("s_waitcnt lgkmcnt(0)" ::: "memory"); \
                        __builtin_amdgcn_sched_barrier(0); } while (0)
#define WAIT_VM4 do { asm volatile("s_waitcnt vmcnt(4)" ::: "memory"); \
                      __builtin_amdgcn_sched_barrier(0); } while (0)
#define WAIT_VM0 do { asm volatile("s_waitcnt vmcnt(0)" ::: "memory"); \
                      __builtin_amdgcn_sched_barrier(0); } while (0)

// ---------- bf16 MFMA GEMM: 256x256 tile, BK=32, counted-vmcnt dbuf ----------
__launch_bounds__(512, 2)
__global__ void k_gemm(const unsigned short* __restrict__ xb,
                       const unsigned short* __restrict__ eb,
                       unsigned* pout /* aliases d_out */) {
    // staging: slot s (s=0,1) at s*32768: A 16 KB (256 rows x 64 B) then B 16 KB.
    // epilogue reuses all 64 KB as uint2 table [128][64].
    __shared__ __align__(16) char smem[65536];

    const int tid = threadIdx.x;
    const int w = tid >> 6, l = tid & 63;
    const int wr = w >> 2, wc = w & 3;        // wave tile: rows wr*128, cols wc*64
    const int lg = l >> 4, lr = l & 15;
    const int bx = blockIdx.x, by = blockIdx.y;
    const int n0 = by * BM, c0 = bx * BN;

    const f32x4 zero = {0.f, 0.f, 0.f, 0.f};
    f32x4 acc[8][4];
    #pragma unroll
    for (int i = 0; i < 8; ++i)
        #pragma unroll
        for (int j = 0; j < 4; ++j) acc[i][j] = zero;

    // ---- staging: row = 64 B = 4 chunks of 16 B; LDS linear, SOURCE pre-swizzled ----
    // LDS phys chunk (row, p) holds global chunk p ^ ((row>>1)&3)
    const int srow = tid >> 2;                           // 0..127 (per 128-row half)
    const int schk = (tid & 3) ^ ((tid >> 3) & 3);       // pre-swizzled source chunk
    const char* gA = (const char*)xb + (size_t)(n0 + srow) * 512 + schk * 16;
    const char* gB = (const char*)eb + (size_t)(c0 + srow) * 512 + schk * 16;
    const int wb = w * 1024;                             // wave-uniform LDS base

    // 4 gloads per stage: A halves (rows 0-127, 128-255), B halves. kb = t*64.
#define STAGE(slot, t) do {                                                  \
    GLOAD_LDS(gA + (t) * 64,         smem + (slot) * 32768 + wb);            \
    GLOAD_LDS(gA + (t) * 64 + 65536, smem + (slot) * 32768 + 8192 + wb);     \
    GLOAD_LDS(gB + (t) * 64,         smem + (slot) * 32768 + 16384 + wb);    \
    GLOAD_LDS(gB + (t) * 64 + 65536, smem + (slot) * 32768 + 24576 + wb);    \
} while (0)

    // ---- fragment reads: logical chunk lg at phys lg ^ ((lr>>1)&3) ----
    const int chkx = (lr >> 1) & 3;
    const int aoff = (wr * 128 + lr) * 64 + ((lg ^ chkx) * 16);
    const int boff = 16384 + (wc * 64 + lr) * 64 + ((lg ^ chkx) * 16);

    bf16x8 a[8], b[4];
#define READS(slot) do {                                                                  \
    const char* base_ = smem + (slot) * 32768;                                            \
    _Pragma("unroll") for (int mi = 0; mi < 8; ++mi)                                      \
        a[mi] = *reinterpret_cast<const bf16x8*>(base_ + aoff + mi * 1024);               \
    _Pragma("unroll") for (int nj = 0; nj < 4; ++nj)                                      \
        b[nj] = *reinterpret_cast<const bf16x8*>(base_ + boff + nj * 1024);               \
} while (0)

#define MMAS() do {                                                          \
    __builtin_amdgcn_s_setprio(1);                                           \
    _Pragma("unroll") for (int mi = 0; mi < 8; ++mi)                         \
      _Pragma("unroll") for (int nj = 0; nj < 4; ++nj)                       \
        acc[mi][nj] = __builtin_amdgcn_mfma_f32_16x16x32_bf16(a[mi], b[nj], acc[mi][nj], 0, 0, 0); \
    __builtin_amdgcn_s_setprio(0);                                           \
} while (0)

    // ---- pipeline: tiles 0..7; stage t+2 into the slot just read; vmcnt(4) mid-loop ----
    STAGE(0, 0);
    STAGE(1, 1);
    WAIT_VM4; SBAR;                     // tile 0 landed (tile 1 in flight)

    #pragma unroll
    for (int t = 0; t < 8; ++t) {
        const int slot = t & 1;
        READS(slot);
        WAIT_LGKM0;
        SBAR;                           // all waves done reading slot -> safe to overwrite
        if (t + 2 < 8) STAGE(slot, t + 2);
        MMAS();
        if (t < 7) {
            if (t < 6) { WAIT_VM4; } else { WAIT_VM0; }
            SBAR;                       // tile t+1 landed on all waves
        }
    }
    __syncthreads();                    // before smem reuse as epilogue table

    // ---- epilogue: 2 rounds x 128 rows; table [cr][64] uint2, phys slot ^ (cr&15) ----
    uint2* T = (uint2*)smem;
    const int slotW = wc * 16 + lr;
    const unsigned encb = 255u - (unsigned)(wc * 64 + lr);
    #pragma unroll
    for (int half = 0; half < 2; ++half) {
        #pragma unroll
        for (int m = 0; m < 4; ++m) {
            const int mi = half * 4 + m;
            #pragma unroll
            for (int r = 0; r < 4; ++r) {
                unsigned q0 = key32(acc[mi][0][r], encb);
                unsigned q1 = key32(acc[mi][1][r], encb - 16);
                unsigned q2 = key32(acc[mi][2][r], encb - 32);
                unsigned q3 = key32(acc[mi][3][r], encb - 48);
                const unsigned m01 = u32max(q0, q1), n01 = u32min(q0, q1);
                const unsigned m23 = u32max(q2, q3), n23 = u32min(q2, q3);
                const unsigned t1 = u32max(m01, m23);
                const unsigned t2 = u32max(u32min(m01, m23), u32max(n01, n23));
                const int cr = wr * 64 + m * 16 + lg * 4 + r;
                uint2 p; p.x = t1; p.y = t2;
                T[cr * 64 + (slotW ^ (cr & 15))] = p;
            }
        }
        __syncthreads();
        // scan: 4 threads per cr-row, 16 entries each, combine via 2-step shuffle
        {
            const int cr = tid >> 2, q = tid & 3;
            unsigned T1 = 0, T2 = 0;
            #pragma unroll
            for (int i = 0; i < 16; ++i) {
                const uint2 p = T[cr * 64 + ((q * 16 + i) ^ (cr & 15))];
                const unsigned n1 = u32max(T1, p.x);
                const unsigned lo = u32min(T1, p.x);
                T2 = u32max(T2, u32max(lo, p.y));
                T1 = n1;
            }
            #pragma unroll
            for (int off = 1; off < 4; off <<= 1) {
                const unsigned o1 = __shfl_xor(T1, off);
                const unsigned o2 = __shfl_xor(T2, off);
                const unsigned n1 = u32max(T1, o1);
                const unsigned lo = u32min(T1, o1);
                T2 = u32max(u32max(T2, o2), lo);
                T1 = n1;
            }
            if (q == 0) {
                const int row = n0 + (cr >> 6) * 128 + half * 64 + (cr & 63);
                uint2 o; o.x = T1; o.y = T2;
                *reinterpret_cast<uint2*>(pout + (size_t)row * 256 + bx * 2) = o;
            }
        }
        if (half == 0) __syncthreads();  // scan done before round-2 table writes
    }
#undef STAGE
#undef READS
#undef MMAS
}

// ---------- fixup: global top-4 candidates -> exact f32 -> argmax + gather ----------
__global__ void k_fixup(const unsigned* pk,  // == (u32*)d_out, intentionally no restrict
                        const float* __restrict__ x, const float* __restrict__ e,
                        float* out) {
    const int row = blockIdx.x * 4 + (threadIdx.x >> 6);
    const int t   = threadIdx.x & 63;   // key index; col-block = t>>1
    const unsigned k = pk[(size_t)row * 256 + t];
    const int col0 = (t >> 1) * 256 + 255 - (int)(k & 255u);
    unsigned long long kk = ((unsigned long long)(k & 0xFFFFFF00u) << 32) | (unsigned)(~col0);

    int cand[4];
    #pragma unroll
    for (int p = 0; p < 4; ++p) {
        unsigned long long m = kk;
        #pragma unroll
        for (int off = 1; off < 64; off <<= 1) {
            const unsigned long long o = __shfl_xor(m, off);
            if (o > m) m = o;
        }
        cand[p] = (int)(~(unsigned)m) & (CCNT - 1);
        if (kk == m) kk = 0ull;
    }

    const float4 xv = *reinterpret_cast<const float4*>(x + (size_t)row * DDIM + t * 4);
    float best = -INFINITY; int bc = 0x7fffffff;
    #pragma unroll
    for (int p = 0; p < 4; ++p) {
        const int c = cand[p];
        const float4 ev = *reinterpret_cast<const float4*>(e + (size_t)c * DDIM + t * 4);
        float d  = xv.x * ev.x + xv.y * ev.y + xv.z * ev.z + xv.w * ev.w;
        float ss = ev.x * ev.x + ev.y * ev.y + ev.z * ev.z + ev.w * ev.w;
        #pragma unroll
        for (int off = 1; off < 64; off <<= 1) {
            d  += __shfl_xor(d, off);
            ss += __shfl_xor(ss, off);
        }
        const float v = d * (1.0f / fmaxf(sqrtf(ss), 1e-12f));
        if (v > best || (v == best && c < bc)) { best = v; bc = c; }
    }

    if (t == 0) out[(size_t)QROWS * DDIM + row] = (float)bc;
    const float4 q = *reinterpret_cast<const float4*>(e + (size_t)bc * DDIM + t * 4);
    *reinterpret_cast<float4*>(out + (size_t)row * DDIM + t * 4) = q; // overwrites this row's partials only
}

extern "C" void kernel_launch(void* const* d_in, const int* in_sizes, int n_in,
                              void* d_out, int out_size, void* d_ws, size_t ws_size,
                              hipStream_t stream) {
    const float* x = (const float*)d_in[0];
    const float* e = (const float*)d_in[1];
    float* out = (float*)d_out;
    char* ws = (char*)d_ws;

    unsigned short* xb = (unsigned short*)ws;                             // 4 MB
    unsigned short* eb = (unsigned short*)(ws + (size_t)4 * 1024 * 1024); // 4 MB

    k_prep<<<3072, 256, 0, stream>>>(x, xb, e, eb);
    dim3 g2(CBLKS, QROWS / BM);
    k_gemm<<<g2, 512, 0, stream>>>(xb, eb, (unsigned*)d_out);
    k_fixup<<<QROWS / 4, 256, 0, stream>>>((const unsigned*)d_out, x, e, out);
}

// Round 6
// 67.987 us; speedup vs baseline: 1.0049x; 1.0049x over previous
//
#include <hip/hip_runtime.h>
#include <math.h>

// B=8, N=1024, D=256, C=8192
#define QROWS 8192
#define DDIM  256
#define CCNT  8192
#define BM    256
#define BN    256
#define BK    64
#define CBLKS (CCNT / BN)    // 32

typedef __attribute__((ext_vector_type(4))) float f32x4;
typedef __attribute__((ext_vector_type(8))) short bf16x8;

__device__ __forceinline__ unsigned short f2bf(float f) {
    unsigned u = __float_as_uint(f);
    u += 0x7fffu + ((u >> 16) & 1u);          // round-to-nearest-even
    return (unsigned short)(u >> 16);
}
__device__ __forceinline__ unsigned u32max(unsigned a, unsigned b) { return a > b ? a : b; }
__device__ __forceinline__ unsigned u32min(unsigned a, unsigned b) { return a < b ? a : b; }

// u32 key: 24-bit monotone float + 8-bit (255 - local_col); bigger = better, lower col wins ties
__device__ __forceinline__ unsigned key32(float v, unsigned enc) {
    unsigned u = __float_as_uint(v);
    unsigned s = (unsigned)((int)u >> 31);
    return ((u ^ (s | 0x80000000u)) & 0xFFFFFF00u) | enc;
}

// ---------- merged prep: x -> bf16 ; e -> l2-normalized bf16 ----------
__global__ void k_prep(const float* __restrict__ x, unsigned short* __restrict__ xb,
                       const float* __restrict__ e, unsigned short* __restrict__ eb) {
    const int bid = blockIdx.x;
    if (bid < 1024) {                         // x: 1024 blocks, 8 el/thread
        const int i = (bid * 256 + threadIdx.x) * 8;
        const float4 f0 = *reinterpret_cast<const float4*>(x + i);
        const float4 f1 = *reinterpret_cast<const float4*>(x + i + 4);
        uint4 o;
        o.x = f2bf(f0.x) | ((unsigned)f2bf(f0.y) << 16);
        o.y = f2bf(f0.z) | ((unsigned)f2bf(f0.w) << 16);
        o.z = f2bf(f1.x) | ((unsigned)f2bf(f1.y) << 16);
        o.w = f2bf(f1.z) | ((unsigned)f2bf(f1.w) << 16);
        *reinterpret_cast<uint4*>(xb + i) = o;
    } else {                                  // e: 2048 blocks, 4 rows/block
        const int row  = (bid - 1024) * 4 + (threadIdx.x >> 6);
        const int lane = threadIdx.x & 63;
        const float4 v = *reinterpret_cast<const float4*>(e + (size_t)row * DDIM + lane * 4);
        float s = v.x * v.x + v.y * v.y + v.z * v.z + v.w * v.w;
        #pragma unroll
        for (int off = 1; off < 64; off <<= 1) s += __shfl_xor(s, off);
        const float inv = 1.0f / fmaxf(sqrtf(s), 1e-12f);
        ushort4 o;
        o.x = f2bf(v.x * inv); o.y = f2bf(v.y * inv);
        o.z = f2bf(v.z * inv); o.w = f2bf(v.w * inv);
        *reinterpret_cast<ushort4*>(eb + (size_t)row * DDIM + lane * 4) = o;
    }
}

#define GLOAD_LDS(g, s) \
    __builtin_amdgcn_global_load_lds((const __attribute__((address_space(1))) void*)(g), \
                                     (__attribute__((address_space(3))) void*)(s), 16, 0, 0)

#define SBAR do { asm volatile("" ::: "memory"); __builtin_amdgcn_s_barrier(); \
                  asm volatile("" ::: "memory"); } while (0)
#define WAIT_LGKM0 do { asm volatile("s_waitcnt lgkmcnt(0)" ::: "memory"); \
                        __builtin_amdgcn_sched_barrier(0); } while (0)
#define WAIT_VM(n) do { asm volatile("s_waitcnt vmcnt(" #n ")" ::: "memory"); \
                        __builtin_amdgcn_sched_barrier(0); } while (0)

// ---------- bf16 MFMA GEMM: 256x256 tile, BK=64, 4-phase/K-tile interleave ----------
// LDS (dynamic, 128 KB): buf s at s*65536: A 32 KB (256 rows x 128 B) + B 32 KB.
// Epilogue reuses first 64 KB as uint2 table [128][64].
__launch_bounds__(512, 2)
__global__ void k_gemm(const unsigned short* __restrict__ xb,
                       const unsigned short* __restrict__ eb,
                       unsigned* pout /* aliases d_out */) {
    extern __shared__ __align__(16) char smem[];

    const int tid = threadIdx.x;
    const int w = tid >> 6, l = tid & 63;
    const int wr = w >> 2, wc = w & 3;        // wave tile: rows wr*128, cols wc*64
    const int lg = l >> 4, lr = l & 15;
    const int bx = blockIdx.x, by = blockIdx.y;
    const int n0 = by * BM, c0 = bx * BN;

    const f32x4 zero = {0.f, 0.f, 0.f, 0.f};
    f32x4 acc[8][4];
    #pragma unroll
    for (int i = 0; i < 8; ++i)
        #pragma unroll
        for (int j = 0; j < 4; ++j) acc[i][j] = zero;

    // ---- fragment read offsets: row = 128 B = 8 chunks; phys chunk = logical ^ (row&7) ----
    const int aBase = (wr * 128 + lr) * 128;
    const int bBase = 32768 + (wc * 64 + lr) * 128;
    const int pc0 = (lg ^ (lr & 7)) * 16;     // kk=0 chunk byte offset
    const int pc1 = pc0 ^ 64;                 // kk=1 ((lg+4) ^ ..)

    // ---- staging: per K-tile 2048 chunks/matrix; gload q covers phys chunks q*512+w*64+l ----
    // phys chunk p: row=p>>3, physc=p&7, logical chunk = physc ^ (row&7) -> row&7 == l>>3
    const int srow = l >> 3;
    const int scl  = (l & 7) ^ srow;          // pre-swizzled source chunk
    const char* gA = (const char*)xb + (size_t)(n0 + w * 8 + srow) * 512 + scl * 16;
    const char* gB = (const char*)eb + (size_t)(c0 + w * 8 + srow) * 512 + scl * 16;
    const int ldsw = w * 1024;                // wave-uniform LDS chunk base

#define STAGE(bufoff, kt) do {                                                         \
    _Pragma("unroll") for (int q_ = 0; q_ < 4; ++q_)                                   \
        GLOAD_LDS(gA + q_ * 32768 + (kt) * 128, smem + (bufoff) + q_ * 8192 + ldsw);   \
    _Pragma("unroll") for (int q_ = 0; q_ < 4; ++q_)                                   \
        GLOAD_LDS(gB + q_ * 32768 + (kt) * 128, smem + (bufoff) + 32768 + q_ * 8192 + ldsw); \
} while (0)

    bf16x8 a[4], b[4];
#define READ_A(bufoff, h, pc) do {                                                     \
    _Pragma("unroll") for (int mi_ = 0; mi_ < 4; ++mi_)                                \
        a[mi_] = *reinterpret_cast<const bf16x8*>(smem + (bufoff) + aBase + ((h) * 4 + mi_) * 2048 + (pc)); \
} while (0)
#define READ_B(bufoff, pc) do {                                                        \
    _Pragma("unroll") for (int nj_ = 0; nj_ < 4; ++nj_)                                \
        b[nj_] = *reinterpret_cast<const bf16x8*>(smem + (bufoff) + bBase + nj_ * 2048 + (pc)); \
} while (0)
#define MMA(h) do {                                                                    \
    __builtin_amdgcn_s_setprio(1);                                                     \
    _Pragma("unroll") for (int mi_ = 0; mi_ < 4; ++mi_)                                \
      _Pragma("unroll") for (int nj_ = 0; nj_ < 4; ++nj_)                              \
        acc[(h) * 4 + mi_][nj_] = __builtin_amdgcn_mfma_f32_16x16x32_bf16(a[mi_], b[nj_], acc[(h) * 4 + mi_][nj_], 0, 0, 0); \
    __builtin_amdgcn_s_setprio(0);                                                     \
} while (0)

    // ---- prologue: stage tiles 0,1; wait tile 0 landed (tile 1 stays in flight) ----
    STAGE(0, 0);
    STAGE(65536, 1);
    WAIT_VM(8);
    SBAR;

    // ---- main loop: 4 K-tiles x 4 phases; 2 barriers/phase; vmcnt drains at tile end ----
    #pragma unroll
    for (int kt = 0; kt < 4; ++kt) {
        const int bo = (kt & 1) * 65536;
        // q0: (kk0, h0) + burst-stage tile kt+1's successor
        READ_B(bo, pc0); READ_A(bo, 0, pc0);
        if (kt == 1) STAGE(0, 2);
        if (kt == 2) STAGE(65536, 3);
        SBAR; WAIT_LGKM0; MMA(0); SBAR;
        // q1: (kk0, h1) — b[] held in regs
        READ_A(bo, 1, pc0);
        SBAR; WAIT_LGKM0; MMA(1); SBAR;
        // q2: (kk1, h0)
        READ_B(bo, pc1); READ_A(bo, 0, pc1);
        SBAR; WAIT_LGKM0; MMA(0); SBAR;
        // q3: (kk1, h1); ensure next tile landed before its q0 reads
        READ_A(bo, 1, pc1);
        SBAR; WAIT_LGKM0; MMA(1);
        if (kt < 3) WAIT_VM(0);
        SBAR;
    }
    __syncthreads();                    // before smem reuse as epilogue table

    // ---- epilogue: 2 rounds x 128 rows; table [cr][64] uint2, phys slot ^ (cr&15) ----
    uint2* T = (uint2*)smem;
    const int slotW = wc * 16 + lr;
    const unsigned encb = 255u - (unsigned)(wc * 64 + lr);
    #pragma unroll
    for (int half = 0; half < 2; ++half) {
        #pragma unroll
        for (int m = 0; m < 4; ++m) {
            const int mi = half * 4 + m;
            #pragma unroll
            for (int r = 0; r < 4; ++r) {
                unsigned q0 = key32(acc[mi][0][r], encb);
                unsigned q1 = key32(acc[mi][1][r], encb - 16);
                unsigned q2 = key32(acc[mi][2][r], encb - 32);
                unsigned q3 = key32(acc[mi][3][r], encb - 48);
                const unsigned m01 = u32max(q0, q1), n01 = u32min(q0, q1);
                const unsigned m23 = u32max(q2, q3), n23 = u32min(q2, q3);
                const unsigned t1 = u32max(m01, m23);
                const unsigned t2 = u32max(u32min(m01, m23), u32max(n01, n23));
                const int cr = wr * 64 + m * 16 + lg * 4 + r;
                uint2 p; p.x = t1; p.y = t2;
                T[cr * 64 + (slotW ^ (cr & 15))] = p;
            }
        }
        __syncthreads();
        // scan: 4 threads per cr-row, 16 entries each, combine via 2-step shuffle
        {
            const int cr = tid >> 2, q = tid & 3;
            unsigned T1 = 0, T2 = 0;
            #pragma unroll
            for (int i = 0; i < 16; ++i) {
                const uint2 p = T[cr * 64 + ((q * 16 + i) ^ (cr & 15))];
                const unsigned n1 = u32max(T1, p.x);
                const unsigned lo = u32min(T1, p.x);
                T2 = u32max(T2, u32max(lo, p.y));
                T1 = n1;
            }
            #pragma unroll
            for (int off = 1; off < 4; off <<= 1) {
                const unsigned o1 = __shfl_xor(T1, off);
                const unsigned o2 = __shfl_xor(T2, off);
                const unsigned n1 = u32max(T1, o1);
                const unsigned lo = u32min(T1, o1);
                T2 = u32max(u32max(T2, o2), lo);
                T1 = n1;
            }
            if (q == 0) {
                const int row = n0 + (cr >> 6) * 128 + half * 64 + (cr & 63);
                uint2 o; o.x = T1; o.y = T2;
                *reinterpret_cast<uint2*>(pout + (size_t)row * 256 + bx * 2) = o;
            }
        }
        if (half == 0) __syncthreads();  // scan done before round-2 table writes
    }
#undef STAGE
#undef READ_A
#undef READ_B
#undef MMA
}

// ---------- fixup: global top-4 candidates -> exact f32 -> argmax + gather ----------
__global__ void k_fixup(const unsigned* pk,  // == (u32*)d_out, intentionally no restrict
                        const float* __restrict__ x, const float* __restrict__ e,
                        float* out) {
    const int row = blockIdx.x * 4 + (threadIdx.x >> 6);
    const int t   = threadIdx.x & 63;   // key index; col-block = t>>1
    const unsigned k = pk[(size_t)row * 256 + t];
    const int col0 = (t >> 1) * 256 + 255 - (int)(k & 255u);
    unsigned long long kk = ((unsigned long long)(k & 0xFFFFFF00u) << 32) | (unsigned)(~col0);

    int cand[4];
    #pragma unroll
    for (int p = 0; p < 4; ++p) {
        unsigned long long m = kk;
        #pragma unroll
        for (int off = 1; off < 64; off <<= 1) {
            const unsigned long long o = __shfl_xor(m, off);
            if (o > m) m = o;
        }
        cand[p] = (int)(~(unsigned)m) & (CCNT - 1);
        if (kk == m) kk = 0ull;
    }

    const float4 xv = *reinterpret_cast<const float4*>(x + (size_t)row * DDIM + t * 4);
    float best = -INFINITY; int bc = 0x7fffffff;
    #pragma unroll
    for (int p = 0; p < 4; ++p) {
        const int c = cand[p];
        const float4 ev = *reinterpret_cast<const float4*>(e + (size_t)c * DDIM + t * 4);
        float d  = xv.x * ev.x + xv.y * ev.y + xv.z * ev.z + xv.w * ev.w;
        float ss = ev.x * ev.x + ev.y * ev.y + ev.z * ev.z + ev.w * ev.w;
        #pragma unroll
        for (int off = 1; off < 64; off <<= 1) {
            d  += __shfl_xor(d, off);
            ss += __shfl_xor(ss, off);
        }
        const float v = d * (1.0f / fmaxf(sqrtf(ss), 1e-12f));
        if (v > best || (v == best && c < bc)) { best = v; bc = c; }
    }

    if (t == 0) out[(size_t)QROWS * DDIM + row] = (float)bc;
    const float4 q = *reinterpret_cast<const float4*>(e + (size_t)bc * DDIM + t * 4);
    *reinterpret_cast<float4*>(out + (size_t)row * DDIM + t * 4) = q; // overwrites this row's partials only
}

extern "C" void kernel_launch(void* const* d_in, const int* in_sizes, int n_in,
                              void* d_out, int out_size, void* d_ws, size_t ws_size,
                              hipStream_t stream) {
    const float* x = (const float*)d_in[0];
    const float* e = (const float*)d_in[1];
    float* out = (float*)d_out;
    char* ws = (char*)d_ws;

    unsigned short* xb = (unsigned short*)ws;                             // 4 MB
    unsigned short* eb = (unsigned short*)(ws + (size_t)4 * 1024 * 1024); // 4 MB

    hipFuncSetAttribute(reinterpret_cast<const void*>(k_gemm),
                        hipFuncAttributeMaxDynamicSharedMemorySize, 131072);

    k_prep<<<3072, 256, 0, stream>>>(x, xb, e, eb);
    dim3 g2(CBLKS, QROWS / BM);
    k_gemm<<<g2, 512, 131072, stream>>>(xb, eb, (unsigned*)d_out);
    k_fixup<<<QROWS / 4, 256, 0, stream>>>((const unsigned*)d_out, x, e, out);
}

// Round 9
// 67.461 us; speedup vs baseline: 1.0127x; 1.0078x over previous
//
#include <hip/hip_runtime.h>
#include <math.h>

// B=8, N=1024, D=256, C=8192
#define QROWS 8192
#define DDIM  256
#define CCNT  8192

typedef __attribute__((ext_vector_type(4))) float f32x4;
typedef __attribute__((ext_vector_type(8))) short bf16x8;

__device__ __forceinline__ unsigned short f2bf(float f) {
    unsigned u = __float_as_uint(f);
    u += 0x7fffu + ((u >> 16) & 1u);          // round-to-nearest-even
    return (unsigned short)(u >> 16);
}
__device__ __forceinline__ unsigned u32max(unsigned a, unsigned b) { return a > b ? a : b; }
__device__ __forceinline__ unsigned u32min(unsigned a, unsigned b) { return a < b ? a : b; }

// sign-folded monotone float bits (relative precision preserved), 24 value bits + 8-bit enc
__device__ __forceinline__ unsigned key32(float v, unsigned enc) {
    unsigned u = __float_as_uint(v);
    unsigned s = (unsigned)((int)u >> 31);
    return ((u ^ (s | 0x80000000u)) & 0xFFFFFF00u) | enc;
}

// ---------- merged prep: x -> bf16 ; e -> l2-normalized bf16 ----------
__global__ void k_prep(const float* __restrict__ x, unsigned short* __restrict__ xb,
                       const float* __restrict__ e, unsigned short* __restrict__ eb) {
    const int bid = blockIdx.x;
    if (bid < 1024) {                         // x: 1024 blocks, 8 el/thread
        const int i = (bid * 256 + threadIdx.x) * 8;
        const float4 f0 = *reinterpret_cast<const float4*>(x + i);
        const float4 f1 = *reinterpret_cast<const float4*>(x + i + 4);
        uint4 o;
        o.x = f2bf(f0.x) | ((unsigned)f2bf(f0.y) << 16);
        o.y = f2bf(f0.z) | ((unsigned)f2bf(f0.w) << 16);
        o.z = f2bf(f1.x) | ((unsigned)f2bf(f1.y) << 16);
        o.w = f2bf(f1.z) | ((unsigned)f2bf(f1.w) << 16);
        *reinterpret_cast<uint4*>(xb + i) = o;
    } else {                                  // e: 2048 blocks, 4 rows/block
        const int row  = (bid - 1024) * 4 + (threadIdx.x >> 6);
        const int lane = threadIdx.x & 63;
        const float4 v = *reinterpret_cast<const float4*>(e + (size_t)row * DDIM + lane * 4);
        float s = v.x * v.x + v.y * v.y + v.z * v.z + v.w * v.w;
        #pragma unroll
        for (int off = 1; off < 64; off <<= 1) s += __shfl_xor(s, off);
        const float inv = 1.0f / fmaxf(sqrtf(s), 1e-12f);
        ushort4 o;
        o.x = f2bf(v.x * inv); o.y = f2bf(v.y * inv);
        o.z = f2bf(v.z * inv); o.w = f2bf(v.w * inv);
        *reinterpret_cast<ushort4*>(eb + (size_t)row * DDIM + lane * 4) = o;
    }
}

#define GLOAD_LDS(g, s) \
    __builtin_amdgcn_global_load_lds((const __attribute__((address_space(1))) void*)(g), \
                                     (__attribute__((address_space(3))) void*)(s), 16, 0, 0)

#define SBAR do { asm volatile("" ::: "memory"); __builtin_amdgcn_s_barrier(); \
                  asm volatile("" ::: "memory"); } while (0)
#define WAIT_LGKM(n) do { asm volatile("s_waitcnt lgkmcnt(" #n ")" ::: "memory"); \
                          __builtin_amdgcn_sched_barrier(0); } while (0)
#define WAIT_VM(n) do { asm volatile("s_waitcnt vmcnt(" #n ")" ::: "memory"); \
                        __builtin_amdgcn_sched_barrier(0); } while (0)

// ---------- GEMM: A panel in REGISTERS (64 rows x K=256 per wave); B streamed ----------
// grid 256 = 16 panels x 16 col-splits; block = 8 waves x 64 rows = 512 rows x 512 cols.
// LDS 128 KB: A-prologue dbuf 2 x 32 KB at [0,64K); B ring 4 x 16 KB at [64K,128K).
// Rows are 512 B = 32 chunks of 16 B; phys chunk = logical ^ (row&7) (both A and B).
__launch_bounds__(512, 2)
__global__ void k_gemm(const unsigned short* __restrict__ xb,
                       const unsigned short* __restrict__ eb,
                       unsigned* pout /* aliases d_out */) {
    extern __shared__ char smem[];

    const int tid = threadIdx.x;
    const int w = tid >> 6, l = tid & 63;
    const int lg = l >> 4, lr = l & 15;
    const int bid = blockIdx.x;
    const int panel = (bid & 7) * 2 + ((bid >> 3) >> 4);   // XCD x shares 2 panels
    const int split = (bid >> 3) & 15;
    const int n0 = panel * 512, c0 = split * 512;

    // ---- staging lane constants (identical pattern for A rounds & B tiles) ----
    const int arl = w * 2 + (l >> 5);
    const size_t soff = (size_t)(((l & 31) ^ (arl & 7)) * 16);
    const char* gApro = (const char*)xb + (size_t)(n0 + arl) * 512 + soff;
    const char* gBpro = (const char*)eb + (size_t)(c0 + arl) * 512 + soff;
    const int wlds = w * 1024;

#define STAGEA(r) do { _Pragma("unroll") for (int g_ = 0; g_ < 4; ++g_)                    \
    GLOAD_LDS(gApro + (r) * 32768 + g_ * 8192,                                             \
              smem + ((r) & 1) * 32768 + g_ * 8192 + wlds); } while (0)
#define STAGEB(t) do { _Pragma("unroll") for (int g_ = 0; g_ < 2; ++g_)                    \
    GLOAD_LDS(gBpro + (size_t)(t) * 16384 + g_ * 8192,                                     \
              smem + 65536 + ((t) & 3) * 16384 + g_ * 8192 + wlds); } while (0)

    bf16x8 aF[4][8];   // [mi][kk]: 64 rows x 256 K per wave, 128 VGPRs
#define READA(slot) do { _Pragma("unroll") for (int mi_ = 0; mi_ < 4; ++mi_)               \
    _Pragma("unroll") for (int kk_ = 0; kk_ < 8; ++kk_)                                    \
        aF[mi_][kk_] = *reinterpret_cast<const bf16x8*>(smem + (slot) * 32768              \
            + (mi_ * 16 + lr) * 512 + (((kk_ * 4 + lg) ^ (lr & 7)) * 16)); } while (0)

    // ---- prologue: 8 A rounds (dbuf), B tiles 0..3 staged up front ----
    STAGEA(0); STAGEA(1);
    STAGEB(0); STAGEB(1); STAGEB(2); STAGEB(3);        // 16 vmem in flight
    WAIT_VM(12); SBAR;  if (w == 0) READA(0);  WAIT_LGKM(0); SBAR; STAGEA(2);
    WAIT_VM(12); SBAR;  if (w == 1) READA(1);  WAIT_LGKM(0); SBAR; STAGEA(3);
    WAIT_VM(4);  SBAR;  if (w == 2) READA(0);  WAIT_LGKM(0); SBAR; STAGEA(4);
    WAIT_VM(4);  SBAR;  if (w == 3) READA(1);  WAIT_LGKM(0); SBAR; STAGEA(5);
    WAIT_VM(4);  SBAR;  if (w == 4) READA(0);  WAIT_LGKM(0); SBAR; STAGEA(6);
    WAIT_VM(4);  SBAR;  if (w == 5) READA(1);  WAIT_LGKM(0); SBAR; STAGEA(7);
    WAIT_VM(4);  SBAR;  if (w == 6) READA(0);  WAIT_LGKM(0); SBAR;
    WAIT_VM(0);  SBAR;  if (w == 7) READA(1);  WAIT_LGKM(0); SBAR;

    // ---- main loop: 16 B tiles of 32 cols; frag-dbuf per kk; stage t+4 after drain ----
    const f32x4 zf4 = {0.f, 0.f, 0.f, 0.f};
    f32x4 acc[4][2];
    #pragma unroll
    for (int i = 0; i < 4; ++i) { acc[i][0] = zf4; acc[i][1] = zf4; }
    unsigned rk1[16], rk2[16];
    #pragma unroll
    for (int i = 0; i < 16; ++i) { rk1[i] = 0u; rk2[i] = 0u; }
    bf16x8 bF[2][2];
    const int bcol0 = lr * 512;        // (nj*16+lr)*512, nj term added per read
    const int cxor = lr & 7;

// flush: merge the 16 lr-lanes' running top-2, store this half's partials, reset
#define FLUSH(half) do {                                                                   \
    _Pragma("unroll") for (int i_ = 0; i_ < 16; ++i_) {                                    \
        unsigned t1_ = rk1[i_], t2_ = rk2[i_];                                             \
        _Pragma("unroll") for (int off_ = 1; off_ < 16; off_ <<= 1) {                      \
            const unsigned o1_ = __shfl_xor(t1_, off_);                                    \
            const unsigned o2_ = __shfl_xor(t2_, off_);                                    \
            const unsigned n1_ = u32max(t1_, o1_), lo_ = u32min(t1_, o1_);                 \
            t2_ = u32max(u32max(t2_, o2_), lo_);                                           \
            t1_ = n1_;                                                                     \
        }                                                                                  \
        if (lr == 0) {                                                                     \
            const int row_ = n0 + w * 64 + (i_ >> 2) * 16 + lg * 4 + (i_ & 3);             \
            uint2 o_; o_.x = t1_; o_.y = t2_;                                              \
            *reinterpret_cast<uint2*>(pout + (size_t)row_ * 256 + split * 4 + (half) * 2) = o_; \
        }                                                                                  \
        rk1[i_] = 0u; rk2[i_] = 0u;                                                        \
    }                                                                                      \
} while (0)

    #pragma unroll 1
    for (int t = 0; t < 16; ++t) {
        const char* sb = smem + 65536 + (t & 3) * 16384;
        #pragma unroll
        for (int nj = 0; nj < 2; ++nj)
            bF[0][nj] = *reinterpret_cast<const bf16x8*>(sb + nj * 8192 + bcol0 + ((lg ^ cxor) * 16));
        #pragma unroll
        for (int kk = 0; kk < 8; ++kk) {
            if (kk < 7) {
                #pragma unroll
                for (int nj = 0; nj < 2; ++nj)
                    bF[(kk + 1) & 1][nj] = *reinterpret_cast<const bf16x8*>(
                        sb + nj * 8192 + bcol0 + ((((kk + 1) * 4 + lg) ^ cxor) * 16));
                WAIT_LGKM(2);
            } else {
                WAIT_LGKM(0);
            }
            __builtin_amdgcn_s_setprio(1);
            #pragma unroll
            for (int mi = 0; mi < 4; ++mi)
                #pragma unroll
                for (int nj = 0; nj < 2; ++nj)
                    acc[mi][nj] = __builtin_amdgcn_mfma_f32_16x16x32_bf16(
                        aF[mi][kk], bF[kk & 1][nj], acc[mi][nj], 0, 0, 0);
            __builtin_amdgcn_s_setprio(0);
        }
        SBAR;                                  // all waves done reading slot t&3
        if (t < 12) STAGEB(t + 4);             // same slot, now safe to overwrite

        // TILEEND: sign-folded 24-bit value + 8-bit (255 - col-within-half) -> running top-2
        const unsigned encb = (unsigned)(255 - (t & 7) * 32) - (unsigned)lr;
        #pragma unroll
        for (int mi = 0; mi < 4; ++mi)
            #pragma unroll
            for (int rr = 0; rr < 4; ++rr) {
                const unsigned q0 = key32(acc[mi][0][rr], encb);
                const unsigned q1 = key32(acc[mi][1][rr], encb - 16u);
                const unsigned m01 = u32max(q0, q1), n01 = u32min(q0, q1);
                const int i = mi * 4 + rr;
                const unsigned lo = u32min(rk1[i], m01);
                rk1[i] = u32max(rk1[i], m01);
                rk2[i] = u32max(u32max(rk2[i], n01), lo);
                acc[mi][0][rr] = 0.0f; acc[mi][1][rr] = 0.0f;
            }
        if (t == 7) FLUSH(0);                  // first 256-col half done
        if (t == 15) FLUSH(1);                 // second half
        if (t < 15) {
            if (t < 12) { WAIT_VM(6); } else { WAIT_VM(0); }   // B_{t+1} landed
            SBAR;                                              // ... on all waves
        }
    }
#undef STAGEA
#undef STAGEB
#undef READA
#undef FLUSH
}

// ---------- fixup: global top-4 of 64 keys -> exact f32 -> argmax + gather ----------
__global__ void k_fixup(const unsigned* pk,  // == (u32*)d_out, intentionally no restrict
                        const float* __restrict__ x, const float* __restrict__ e,
                        float* out) {
    const int row = blockIdx.x * 4 + (threadIdx.x >> 6);
    const int t   = threadIdx.x & 63;   // t<32: half-split partial holder (256 cols each)
    unsigned long long kk0 = 0ull, kk1 = 0ull;
    if (t < 32) {
        const uint2 kv = reinterpret_cast<const uint2*>(pk + (size_t)row * 256)[t];
        const int col0 = t * 256 + 255 - (int)(kv.x & 255u);
        kk0 = ((unsigned long long)(kv.x & 0xFFFFFF00u) << 32) | (unsigned)(~col0);
        const int col1 = t * 256 + 255 - (int)(kv.y & 255u);
        kk1 = ((unsigned long long)(kv.y & 0xFFFFFF00u) << 32) | (unsigned)(~col1);
    }

    int cand[4];
    #pragma unroll
    for (int p = 0; p < 4; ++p) {
        unsigned long long m = kk0 > kk1 ? kk0 : kk1;
        #pragma unroll
        for (int off = 1; off < 64; off <<= 1) {
            const unsigned long long o = __shfl_xor(m, off);
            if (o > m) m = o;
        }
        cand[p] = (int)(~(unsigned)m) & (CCNT - 1);
        if (kk0 == m) kk0 = 0ull;
        if (kk1 == m) kk1 = 0ull;
    }

    const float4 xv = *reinterpret_cast<const float4*>(x + (size_t)row * DDIM + t * 4);
    float best = -INFINITY; int bc = 0x7fffffff;
    #pragma unroll
    for (int p = 0; p < 4; ++p) {
        const int c = cand[p];
        const float4 ev = *reinterpret_cast<const float4*>(e + (size_t)c * DDIM + t * 4);
        float d  = xv.x * ev.x + xv.y * ev.y + xv.z * ev.z + xv.w * ev.w;
        float ss = ev.x * ev.x + ev.y * ev.y + ev.z * ev.z + ev.w * ev.w;
        #pragma unroll
        for (int off = 1; off < 64; off <<= 1) {
            d  += __shfl_xor(d, off);
            ss += __shfl_xor(ss, off);
        }
        const float v = d * (1.0f / fmaxf(sqrtf(ss), 1e-12f));
        if (v > best || (v == best && c < bc)) { best = v; bc = c; }
    }

    if (t == 0) out[(size_t)QROWS * DDIM + row] = (float)bc;
    const float4 q = *reinterpret_cast<const float4*>(e + (size_t)bc * DDIM + t * 4);
    *reinterpret_cast<float4*>(out + (size_t)row * DDIM + t * 4) = q; // overwrites this row's partials only
}

extern "C" void kernel_launch(void* const* d_in, const int* in_sizes, int n_in,
                              void* d_out, int out_size, void* d_ws, size_t ws_size,
                              hipStream_t stream) {
    const float* x = (const float*)d_in[0];
    const float* e = (const float*)d_in[1];
    float* out = (float*)d_out;
    char* ws = (char*)d_ws;

    unsigned short* xb = (unsigned short*)ws;                             // 4 MB
    unsigned short* eb = (unsigned short*)(ws + (size_t)4 * 1024 * 1024); // 4 MB

    hipFuncSetAttribute(reinterpret_cast<const void*>(k_gemm),
                        hipFuncAttributeMaxDynamicSharedMemorySize, 131072);

    k_prep<<<3072, 256, 0, stream>>>(x, xb, e, eb);
    k_gemm<<<256, 512, 131072, stream>>>(xb, eb, (unsigned*)d_out);
    k_fixup<<<QROWS / 4, 256, 0, stream>>>((const unsigned*)d_out, x, e, out);
}

// Round 10
// 65.260 us; speedup vs baseline: 1.0469x; 1.0337x over previous
//
#include <hip/hip_runtime.h>
#include <math.h>

// B=8, N=1024, D=256, C=8192
#define QROWS 8192
#define DDIM  256
#define CCNT  8192

typedef __attribute__((ext_vector_type(4))) float f32x4;
typedef __attribute__((ext_vector_type(8))) short bf16x8;

__device__ __forceinline__ unsigned short f2bf(float f) {
    unsigned u = __float_as_uint(f);
    u += 0x7fffu + ((u >> 16) & 1u);          // round-to-nearest-even
    return (unsigned short)(u >> 16);
}
__device__ __forceinline__ unsigned u32max(unsigned a, unsigned b) { return a > b ? a : b; }
__device__ __forceinline__ unsigned u32min(unsigned a, unsigned b) { return a < b ? a : b; }

// sign-folded monotone float bits (relative precision preserved), 24 value bits + 8-bit enc
__device__ __forceinline__ unsigned key32(float v, unsigned enc) {
    unsigned u = __float_as_uint(v);
    unsigned s = (unsigned)((int)u >> 31);
    return ((u ^ (s | 0x80000000u)) & 0xFFFFFF00u) | enc;
}

// ---------- merged prep: x -> bf16 ; e -> l2-normalized bf16 ----------
__global__ void k_prep(const float* __restrict__ x, unsigned short* __restrict__ xb,
                       const float* __restrict__ e, unsigned short* __restrict__ eb) {
    const int bid = blockIdx.x;
    if (bid < 1024) {                         // x: 1024 blocks, 8 el/thread
        const int i = (bid * 256 + threadIdx.x) * 8;
        const float4 f0 = *reinterpret_cast<const float4*>(x + i);
        const float4 f1 = *reinterpret_cast<const float4*>(x + i + 4);
        uint4 o;
        o.x = f2bf(f0.x) | ((unsigned)f2bf(f0.y) << 16);
        o.y = f2bf(f0.z) | ((unsigned)f2bf(f0.w) << 16);
        o.z = f2bf(f1.x) | ((unsigned)f2bf(f1.y) << 16);
        o.w = f2bf(f1.z) | ((unsigned)f2bf(f1.w) << 16);
        *reinterpret_cast<uint4*>(xb + i) = o;
    } else {                                  // e: 2048 blocks, 4 rows/block
        const int row  = (bid - 1024) * 4 + (threadIdx.x >> 6);
        const int lane = threadIdx.x & 63;
        const float4 v = *reinterpret_cast<const float4*>(e + (size_t)row * DDIM + lane * 4);
        float s = v.x * v.x + v.y * v.y + v.z * v.z + v.w * v.w;
        #pragma unroll
        for (int off = 1; off < 64; off <<= 1) s += __shfl_xor(s, off);
        const float inv = 1.0f / fmaxf(sqrtf(s), 1e-12f);
        ushort4 o;
        o.x = f2bf(v.x * inv); o.y = f2bf(v.y * inv);
        o.z = f2bf(v.z * inv); o.w = f2bf(v.w * inv);
        *reinterpret_cast<ushort4*>(eb + (size_t)row * DDIM + lane * 4) = o;
    }
}

#define GLOAD_LDS(g, s) \
    __builtin_amdgcn_global_load_lds((const __attribute__((address_space(1))) void*)(g), \
                                     (__attribute__((address_space(3))) void*)(s), 16, 0, 0)

#define SBAR do { asm volatile("" ::: "memory"); __builtin_amdgcn_s_barrier(); \
                  asm volatile("" ::: "memory"); } while (0)
#define WAIT_LGKM(n) do { asm volatile("s_waitcnt lgkmcnt(" #n ")" ::: "memory"); \
                          __builtin_amdgcn_sched_barrier(0); } while (0)
#define WAIT_VM(n) do { asm volatile("s_waitcnt vmcnt(" #n ")" ::: "memory"); \
                        __builtin_amdgcn_sched_barrier(0); } while (0)

// ---------- GEMM: A in registers; B streamed; ONE barrier per tile ----------
// grid 256 = 16 panels x 16 col-splits; block = 8 waves x 64 rows = 512 rows x 512 cols.
// LDS 128 KB: A-prologue dbuf 2 x 32 KB at [0,64K); B ring 4 x 16 KB at [64K,128K).
// Rows are 512 B = 32 chunks of 16 B; phys chunk = logical ^ (row&7) (both A and B).
// Sync design: per tile: WAIT_VM(4) retires stage(t) [issued t-3] -> SBAR -> STAGE(t+3)
// -> frag reads (2-kk-ahead ring) -> MFMA -> TILEEND. No second barrier: waves drift
// within the tile window so TILEEND VALU overlaps other waves' MFMA bursts.
__launch_bounds__(512, 2)
__global__ void k_gemm(const unsigned short* __restrict__ xb,
                       const unsigned short* __restrict__ eb,
                       unsigned* pout /* aliases d_out */) {
    extern __shared__ char smem[];

    const int tid = threadIdx.x;
    const int w = tid >> 6, l = tid & 63;
    const int lg = l >> 4, lr = l & 15;
    const int bid = blockIdx.x;
    const int panel = (bid & 7) * 2 + ((bid >> 3) >> 4);   // XCD x shares 2 panels
    const int split = (bid >> 3) & 15;
    const int n0 = panel * 512, c0 = split * 512;

    // ---- staging lane constants (identical pattern for A rounds & B tiles) ----
    const int arl = w * 2 + (l >> 5);
    const size_t soff = (size_t)(((l & 31) ^ (arl & 7)) * 16);
    const char* gApro = (const char*)xb + (size_t)(n0 + arl) * 512 + soff;
    const char* gBpro = (const char*)eb + (size_t)(c0 + arl) * 512 + soff;
    const int wlds = w * 1024;

#define STAGEA(r) do { _Pragma("unroll") for (int g_ = 0; g_ < 4; ++g_)                    \
    GLOAD_LDS(gApro + (r) * 32768 + g_ * 8192,                                             \
              smem + ((r) & 1) * 32768 + g_ * 8192 + wlds); } while (0)
#define STAGEB(t) do { _Pragma("unroll") for (int g_ = 0; g_ < 2; ++g_)                    \
    GLOAD_LDS(gBpro + (size_t)(t) * 16384 + g_ * 8192,                                     \
              smem + 65536 + ((t) & 3) * 16384 + g_ * 8192 + wlds); } while (0)

    bf16x8 aF[4][8];   // [mi][kk]: 64 rows x 256 K per wave, 128 VGPRs
#define READA(slot) do { _Pragma("unroll") for (int mi_ = 0; mi_ < 4; ++mi_)               \
    _Pragma("unroll") for (int kk_ = 0; kk_ < 8; ++kk_)                                    \
        aF[mi_][kk_] = *reinterpret_cast<const bf16x8*>(smem + (slot) * 32768              \
            + (mi_ * 16 + lr) * 512 + (((kk_ * 4 + lg) ^ (lr & 7)) * 16)); } while (0)

    // ---- prologue: 8 A rounds (dbuf), B tiles 0..3 staged up front ----
    STAGEA(0); STAGEA(1);
    STAGEB(0); STAGEB(1); STAGEB(2); STAGEB(3);        // 16 vmem in flight
    WAIT_VM(12); SBAR;  if (w == 0) READA(0);  WAIT_LGKM(0); SBAR; STAGEA(2);
    WAIT_VM(12); SBAR;  if (w == 1) READA(1);  WAIT_LGKM(0); SBAR; STAGEA(3);
    WAIT_VM(4);  SBAR;  if (w == 2) READA(0);  WAIT_LGKM(0); SBAR; STAGEA(4);
    WAIT_VM(4);  SBAR;  if (w == 3) READA(1);  WAIT_LGKM(0); SBAR; STAGEA(5);
    WAIT_VM(4);  SBAR;  if (w == 4) READA(0);  WAIT_LGKM(0); SBAR; STAGEA(6);
    WAIT_VM(4);  SBAR;  if (w == 5) READA(1);  WAIT_LGKM(0); SBAR; STAGEA(7);
    WAIT_VM(4);  SBAR;  if (w == 6) READA(0);  WAIT_LGKM(0); SBAR;
    WAIT_VM(0);  SBAR;  if (w == 7) READA(1);  WAIT_LGKM(0); SBAR;
    // state: aF loaded; B tiles 0..3 landed in slots 0..3; vmcnt 0; all waves synced.

    // ---- main loop: 16 B tiles of 32 cols; one barrier/tile; 2-kk-ahead frag ring ----
    const f32x4 zf4 = {0.f, 0.f, 0.f, 0.f};
    f32x4 acc[4][2];
    #pragma unroll
    for (int i = 0; i < 4; ++i) { acc[i][0] = zf4; acc[i][1] = zf4; }
    unsigned rk1[16], rk2[16];
    #pragma unroll
    for (int i = 0; i < 16; ++i) { rk1[i] = 0u; rk2[i] = 0u; }
    bf16x8 bf[3][2];
    const int bcol0 = lr * 512;        // (nj*16+lr)*512, nj term added per read
    const int cxor = lr & 7;

// flush: merge the 16 lr-lanes' running top-2, store this half's partials, reset
#define FLUSH(half) do {                                                                   \
    _Pragma("unroll") for (int i_ = 0; i_ < 16; ++i_) {                                    \
        unsigned t1_ = rk1[i_], t2_ = rk2[i_];                                             \
        _Pragma("unroll") for (int off_ = 1; off_ < 16; off_ <<= 1) {                      \
            const unsigned o1_ = __shfl_xor(t1_, off_);                                    \
            const unsigned o2_ = __shfl_xor(t2_, off_);                                    \
            const unsigned n1_ = u32max(t1_, o1_), lo_ = u32min(t1_, o1_);                 \
            t2_ = u32max(u32max(t2_, o2_), lo_);                                           \
            t1_ = n1_;                                                                     \
        }                                                                                  \
        if (lr == 0) {                                                                     \
            const int row_ = n0 + w * 64 + (i_ >> 2) * 16 + lg * 4 + (i_ & 3);             \
            uint2 o_; o_.x = t1_; o_.y = t2_;                                              \
            *reinterpret_cast<uint2*>(pout + (size_t)row_ * 256 + split * 4 + (half) * 2) = o_; \
        }                                                                                  \
        rk1[i_] = 0u; rk2[i_] = 0u;                                                        \
    }                                                                                      \
} while (0)

    #pragma unroll 1
    for (int t = 0; t < 16; ++t) {
        // retire stage(t) (issued at tile t-3; tiles 0..3 came from the prologue, so
        // the early waits are no-ops). Stores from FLUSH only cause safe over-waits.
        if (t <= 13)      { WAIT_VM(4); }
        else if (t == 14) { WAIT_VM(2); }
        else              { WAIT_VM(0); }
        SBAR;                                   // sole barrier: slot t ready on all waves;
                                                // all waves retired their tile t-1 reads.
        if (t >= 1 && t < 13) STAGEB(t + 3);    // overwrite slot (t-1)&3 — WAR safe.

        const char* sb = smem + 65536 + (t & 3) * 16384;
        // preload frag sets for kk=0,1
        #pragma unroll
        for (int nj = 0; nj < 2; ++nj)
            bf[0][nj] = *reinterpret_cast<const bf16x8*>(sb + nj * 8192 + bcol0 + ((lg ^ cxor) * 16));
        #pragma unroll
        for (int nj = 0; nj < 2; ++nj)
            bf[1][nj] = *reinterpret_cast<const bf16x8*>(sb + nj * 8192 + bcol0 + (((4 + lg) ^ cxor) * 16));

        #pragma unroll
        for (int kk = 0; kk < 8; ++kk) {
            if (kk < 6) {
                #pragma unroll
                for (int nj = 0; nj < 2; ++nj)
                    bf[(kk + 2) % 3][nj] = *reinterpret_cast<const bf16x8*>(
                        sb + nj * 8192 + bcol0 + ((((kk + 2) * 4 + lg) ^ cxor) * 16));
                WAIT_LGKM(4);                   // retire f(kk); f(kk+1),f(kk+2) in flight
            } else if (kk == 6) { WAIT_LGKM(2); } else { WAIT_LGKM(0); }
            __builtin_amdgcn_s_setprio(1);
            #pragma unroll
            for (int mi = 0; mi < 4; ++mi)
                #pragma unroll
                for (int nj = 0; nj < 2; ++nj)
                    acc[mi][nj] = __builtin_amdgcn_mfma_f32_16x16x32_bf16(
                        aF[mi][kk], bf[kk % 3][nj], acc[mi][nj], 0, 0, 0);
            __builtin_amdgcn_s_setprio(0);
        }

        // TILEEND: sign-folded 24-bit value + 8-bit (255 - col-within-half) -> running top-2
        // (no barrier after this: overlaps other waves' MFMA of the same window)
        const unsigned encb = (unsigned)(255 - (t & 7) * 32) - (unsigned)lr;
        #pragma unroll
        for (int mi = 0; mi < 4; ++mi)
            #pragma unroll
            for (int rr = 0; rr < 4; ++rr) {
                const unsigned q0 = key32(acc[mi][0][rr], encb);
                const unsigned q1 = key32(acc[mi][1][rr], encb - 16u);
                const unsigned m01 = u32max(q0, q1), n01 = u32min(q0, q1);
                const int i = mi * 4 + rr;
                const unsigned lo = u32min(rk1[i], m01);
                rk1[i] = u32max(rk1[i], m01);
                rk2[i] = u32max(u32max(rk2[i], n01), lo);
                acc[mi][0][rr] = 0.0f; acc[mi][1][rr] = 0.0f;
            }
        if (t == 7) FLUSH(0);                  // first 256-col half done
        if (t == 15) FLUSH(1);                 // second half
    }
#undef STAGEA
#undef STAGEB
#undef READA
#undef FLUSH
}

// ---------- fixup: global top-4 of 64 keys -> exact f32 -> argmax + gather ----------
__global__ void k_fixup(const unsigned* pk,  // == (u32*)d_out, intentionally no restrict
                        const float* __restrict__ x, const float* __restrict__ e,
                        float* out) {
    const int row = blockIdx.x * 4 + (threadIdx.x >> 6);
    const int t   = threadIdx.x & 63;   // t<32: half-split partial holder (256 cols each)
    unsigned long long kk0 = 0ull, kk1 = 0ull;
    if (t < 32) {
        const uint2 kv = reinterpret_cast<const uint2*>(pk + (size_t)row * 256)[t];
        const int col0 = t * 256 + 255 - (int)(kv.x & 255u);
        kk0 = ((unsigned long long)(kv.x & 0xFFFFFF00u) << 32) | (unsigned)(~col0);
        const int col1 = t * 256 + 255 - (int)(kv.y & 255u);
        kk1 = ((unsigned long long)(kv.y & 0xFFFFFF00u) << 32) | (unsigned)(~col1);
    }

    int cand[4];
    #pragma unroll
    for (int p = 0; p < 4; ++p) {
        unsigned long long m = kk0 > kk1 ? kk0 : kk1;
        #pragma unroll
        for (int off = 1; off < 64; off <<= 1) {
            const unsigned long long o = __shfl_xor(m, off);
            if (o > m) m = o;
        }
        cand[p] = (int)(~(unsigned)m) & (CCNT - 1);
        if (kk0 == m) kk0 = 0ull;
        if (kk1 == m) kk1 = 0ull;
    }

    const float4 xv = *reinterpret_cast<const float4*>(x + (size_t)row * DDIM + t * 4);
    float best = -INFINITY; int bc = 0x7fffffff;
    #pragma unroll
    for (int p = 0; p < 4; ++p) {
        const int c = cand[p];
        const float4 ev = *reinterpret_cast<const float4*>(e + (size_t)c * DDIM + t * 4);
        float d  = xv.x * ev.x + xv.y * ev.y + xv.z * ev.z + xv.w * ev.w;
        float ss = ev.x * ev.x + ev.y * ev.y + ev.z * ev.z + ev.w * ev.w;
        #pragma unroll
        for (int off = 1; off < 64; off <<= 1) {
            d  += __shfl_xor(d, off);
            ss += __shfl_xor(ss, off);
        }
        const float v = d * (1.0f / fmaxf(sqrtf(ss), 1e-12f));
        if (v > best || (v == best && c < bc)) { best = v; bc = c; }
    }

    if (t == 0) out[(size_t)QROWS * DDIM + row] = (float)bc;
    const float4 q = *reinterpret_cast<const float4*>(e + (size_t)bc * DDIM + t * 4);
    *reinterpret_cast<float4*>(out + (size_t)row * DDIM + t * 4) = q; // overwrites this row's partials only
}

extern "C" void kernel_launch(void* const* d_in, const int* in_sizes, int n_in,
                              void* d_out, int out_size, void* d_ws, size_t ws_size,
                              hipStream_t stream) {
    const float* x = (const float*)d_in[0];
    const float* e = (const float*)d_in[1];
    float* out = (float*)d_out;
    char* ws = (char*)d_ws;

    unsigned short* xb = (unsigned short*)ws;                             // 4 MB
    unsigned short* eb = (unsigned short*)(ws + (size_t)4 * 1024 * 1024); // 4 MB

    hipFuncSetAttribute(reinterpret_cast<const void*>(k_gemm),
                        hipFuncAttributeMaxDynamicSharedMemorySize, 131072);

    k_prep<<<3072, 256, 0, stream>>>(x, xb, e, eb);
    k_gemm<<<256, 512, 131072, stream>>>(xb, eb, (unsigned*)d_out);
    k_fixup<<<QROWS / 4, 256, 0, stream>>>((const unsigned*)d_out, x, e, out);
}

// Round 11
// 60.275 us; speedup vs baseline: 1.1335x; 1.0827x over previous
//
#include <hip/hip_runtime.h>
#include <math.h>

// B=8, N=1024, D=256, C=8192
#define QROWS 8192
#define DDIM  256
#define CCNT  8192

typedef __attribute__((ext_vector_type(4))) float f32x4;
typedef __attribute__((ext_vector_type(8))) short bf16x8;

__device__ __forceinline__ unsigned short f2bf(float f) {
    unsigned u = __float_as_uint(f);
    u += 0x7fffu + ((u >> 16) & 1u);          // round-to-nearest-even
    return (unsigned short)(u >> 16);
}
__device__ __forceinline__ unsigned u32max(unsigned a, unsigned b) { return a > b ? a : b; }
__device__ __forceinline__ unsigned u32min(unsigned a, unsigned b) { return a < b ? a : b; }

// sign-folded monotone float bits (relative precision preserved), 24 value bits + 8-bit enc
__device__ __forceinline__ unsigned key32(float v, unsigned enc) {
    unsigned u = __float_as_uint(v);
    unsigned s = (unsigned)((int)u >> 31);
    return ((u ^ (s | 0x80000000u)) & 0xFFFFFF00u) | enc;
}

// ---------- merged prep: x -> bf16 ; e -> l2-normalized bf16 ----------
__global__ void k_prep(const float* __restrict__ x, unsigned short* __restrict__ xb,
                       const float* __restrict__ e, unsigned short* __restrict__ eb) {
    const int bid = blockIdx.x;
    if (bid < 1024) {                         // x: 1024 blocks, 8 el/thread
        const int i = (bid * 256 + threadIdx.x) * 8;
        const float4 f0 = *reinterpret_cast<const float4*>(x + i);
        const float4 f1 = *reinterpret_cast<const float4*>(x + i + 4);
        uint4 o;
        o.x = f2bf(f0.x) | ((unsigned)f2bf(f0.y) << 16);
        o.y = f2bf(f0.z) | ((unsigned)f2bf(f0.w) << 16);
        o.z = f2bf(f1.x) | ((unsigned)f2bf(f1.y) << 16);
        o.w = f2bf(f1.z) | ((unsigned)f2bf(f1.w) << 16);
        *reinterpret_cast<uint4*>(xb + i) = o;
    } else {                                  // e: 2048 blocks, 4 rows/block
        const int row  = (bid - 1024) * 4 + (threadIdx.x >> 6);
        const int lane = threadIdx.x & 63;
        const float4 v = *reinterpret_cast<const float4*>(e + (size_t)row * DDIM + lane * 4);
        float s = v.x * v.x + v.y * v.y + v.z * v.z + v.w * v.w;
        #pragma unroll
        for (int off = 1; off < 64; off <<= 1) s += __shfl_xor(s, off);
        const float inv = 1.0f / fmaxf(sqrtf(s), 1e-12f);
        ushort4 o;
        o.x = f2bf(v.x * inv); o.y = f2bf(v.y * inv);
        o.z = f2bf(v.z * inv); o.w = f2bf(v.w * inv);
        *reinterpret_cast<ushort4*>(eb + (size_t)row * DDIM + lane * 4) = o;
    }
}

#define GLOAD_LDS(g, s) \
    __builtin_amdgcn_global_load_lds((const __attribute__((address_space(1))) void*)(g), \
                                     (__attribute__((address_space(3))) void*)(s), 16, 0, 0)

#define SBAR do { asm volatile("" ::: "memory"); __builtin_amdgcn_s_barrier(); \
                  asm volatile("" ::: "memory"); } while (0)
#define WAIT_LGKM(n) do { asm volatile("s_waitcnt lgkmcnt(" #n ")" ::: "memory"); \
                          __builtin_amdgcn_sched_barrier(0); } while (0)
#define WAIT_VM(n) do { asm volatile("s_waitcnt vmcnt(" #n ")" ::: "memory"); \
                        __builtin_amdgcn_sched_barrier(0); } while (0)

// ---------- GEMM: A in registers; B via 8-slot ring; ONE sync point per 2 tiles ----------
// grid 256 = 16 panels x 16 col-splits; block = 8 waves x 64 rows = 512 rows x 512 cols.
// LDS 128 KB: prologue = two A halves (256 rows x 512 B each), then B ring 8 x 16 KB.
// Rows are 512 B = 32 chunks of 16 B; phys chunk = (l&24)|((l&7)^(row&7)), src pre-swizzled.
// Pair loop u=0..7 (tiles 2u,2u+1): WAIT_VM(counted); SBAR; STAGEB(2u+6),(2u+7); then two
// tiles of compiler-scheduled {ds_read frags + MFMA} + TILEEND. No setprio, no per-kk waits.
__launch_bounds__(512, 2)
__global__ void k_gemm(const unsigned short* __restrict__ xb,
                       const unsigned short* __restrict__ eb,
                       unsigned* pout /* aliases d_out */) {
    extern __shared__ char smem[];

    const int tid = threadIdx.x;
    const int w = tid >> 6, l = tid & 63;
    const int lg = l >> 4, lr = l & 15, lr7 = lr & 7;
    const int bid = blockIdx.x;
    const int panel = (bid & 7) * 2 + ((bid >> 3) >> 4);   // XCD x shares 2 panels
    const int split = (bid >> 3) & 15;
    const int n0 = panel * 512, c0 = split * 512;

    // ---- staging constants: thread covers chunk idx = g*512+tid; row=idx>>5, p=tid&31 ----
    // logical chunk l = (p&24) | ((p&7) ^ (row&7)); row&7 == (tid>>5)&7 for all g (g*16%8==0)
    const int lchk = (tid & 24) | ((tid & 7) ^ ((tid >> 5) & 7));
    const char* baseA = (const char*)xb + (size_t)(n0 + (tid >> 5)) * 512 + lchk * 16;
    const char* baseB = (const char*)eb + (size_t)(c0 + (tid >> 5)) * 512 + lchk * 16;
    const int wl16 = w * 1024;                 // wave-uniform LDS base (lane*16 added by HW)

#define STAGE_AHALF(h) do { _Pragma("unroll") for (int g_ = 0; g_ < 16; ++g_)              \
    GLOAD_LDS(baseA + (h) * 131072 + g_ * 8192, smem + g_ * 8192 + wl16); } while (0)
#define STAGEB(t) do { _Pragma("unroll") for (int g_ = 0; g_ < 2; ++g_)                    \
    GLOAD_LDS(baseB + (size_t)(t) * 16384 + g_ * 8192,                                     \
              smem + ((t) & 7) * 16384 + g_ * 8192 + wl16); } while (0)

    // ---- A fragments: 64 rows x 256 K per wave = 128 VGPR ----
    bf16x8 aF[4][8];
#define READA() do { _Pragma("unroll") for (int mi_ = 0; mi_ < 4; ++mi_)                   \
    _Pragma("unroll") for (int kk_ = 0; kk_ < 8; ++kk_) {                                  \
        const int lc_ = kk_ * 4 + lg;                                                      \
        const int ph_ = (lc_ & 24) | ((lc_ & 7) ^ lr7);                                    \
        aF[mi_][kk_] = *reinterpret_cast<const bf16x8*>(                                   \
            smem + ((w & 3) * 64 + mi_ * 16 + lr) * 512 + ph_ * 16); } } while (0)

    // ---- prologue: two 128-KB A halves, 4 waves read each half in parallel ----
    STAGE_AHALF(0);
    WAIT_VM(0); SBAR;
    if (w < 4) READA();                       // waves 0-3 own rows in half 0
    WAIT_LGKM(0); SBAR;                       // readers drained before overwrite
    STAGE_AHALF(1);
    WAIT_VM(0); SBAR;
    if (w >= 4) READA();                      // waves 4-7 own rows in half 1
    WAIT_LGKM(0); SBAR;
    STAGEB(0); STAGEB(1); STAGEB(2); STAGEB(3); STAGEB(4); STAGEB(5);   // 12 loads in flight

    // ---- main loop state ----
    const f32x4 zf4 = {0.f, 0.f, 0.f, 0.f};
    f32x4 acc[4][2];
    unsigned rk1[16], rk2[16];
    #pragma unroll
    for (int i = 0; i < 16; ++i) { rk1[i] = 0u; rk2[i] = 0u; }

#define TILE(t) do {                                                                       \
    const char* sb_ = smem + ((t) & 7) * 16384;                                            \
    _Pragma("unroll") for (int mi_ = 0; mi_ < 4; ++mi_)                                    \
        { acc[mi_][0] = zf4; acc[mi_][1] = zf4; }                                          \
    _Pragma("unroll") for (int kk_ = 0; kk_ < 8; ++kk_) {                                  \
        const int lc_ = kk_ * 4 + lg;                                                      \
        const int ph_ = ((lc_ & 24) | ((lc_ & 7) ^ lr7)) * 16;                             \
        const bf16x8 b0_ = *reinterpret_cast<const bf16x8*>(sb_ + (lr) * 512 + ph_);       \
        const bf16x8 b1_ = *reinterpret_cast<const bf16x8*>(sb_ + (16 + lr) * 512 + ph_);  \
        _Pragma("unroll") for (int mi_ = 0; mi_ < 4; ++mi_) {                              \
            acc[mi_][0] = __builtin_amdgcn_mfma_f32_16x16x32_bf16(aF[mi_][kk_], b0_, acc[mi_][0], 0, 0, 0); \
            acc[mi_][1] = __builtin_amdgcn_mfma_f32_16x16x32_bf16(aF[mi_][kk_], b1_, acc[mi_][1], 0, 0, 0); \
        } }                                                                                \
    const unsigned encb_ = (unsigned)(255 - ((t) & 7) * 32) - (unsigned)lr;                \
    _Pragma("unroll") for (int mi_ = 0; mi_ < 4; ++mi_)                                    \
        _Pragma("unroll") for (int rr_ = 0; rr_ < 4; ++rr_) {                              \
            const unsigned q0_ = key32(acc[mi_][0][rr_], encb_);                           \
            const unsigned q1_ = key32(acc[mi_][1][rr_], encb_ - 16u);                     \
            const unsigned m01_ = u32max(q0_, q1_), n01_ = u32min(q0_, q1_);               \
            const int i_ = mi_ * 4 + rr_;                                                  \
            const unsigned lo_ = u32min(rk1[i_], m01_);                                    \
            rk1[i_] = u32max(rk1[i_], m01_);                                               \
            rk2[i_] = u32max(u32max(rk2[i_], n01_), lo_);                                  \
        }                                                                                  \
} while (0)

// flush: merge the 16 lr-lanes' running top-2, store this half's partials, reset
#define FLUSH(half) do {                                                                   \
    _Pragma("unroll") for (int i_ = 0; i_ < 16; ++i_) {                                    \
        unsigned t1_ = rk1[i_], t2_ = rk2[i_];                                             \
        _Pragma("unroll") for (int off_ = 1; off_ < 16; off_ <<= 1) {                      \
            const unsigned o1_ = __shfl_xor(t1_, off_);                                    \
            const unsigned o2_ = __shfl_xor(t2_, off_);                                    \
            const unsigned n1_ = u32max(t1_, o1_), lo_ = u32min(t1_, o1_);                 \
            t2_ = u32max(u32max(t2_, o2_), lo_);                                           \
            t1_ = n1_;                                                                     \
        }                                                                                  \
        if (lr == 0) {                                                                     \
            const int row_ = n0 + w * 64 + (i_ >> 2) * 16 + lg * 4 + (i_ & 3);             \
            uint2 o_; o_.x = t1_; o_.y = t2_;                                              \
            *reinterpret_cast<uint2*>(pout + (size_t)row_ * 256 + split * 4 + (half) * 2) = o_; \
        }                                                                                  \
        rk1[i_] = 0u; rk2[i_] = 0u;                                                        \
    }                                                                                      \
} while (0)

    // ---- 8 pairs of tiles; one WAIT_VM+SBAR per pair ----
    // vmcnt trace (per wave): entering u, outstanding = stages 2u..2u+5 (12 loads, + flush
    // stores after u=3). VM(8) retires stages 2u,2u+1 (tail: VM(4)@u6, VM(0)@u7 — flush
    // stores absorbed at u=4/5/6 waits as analyzed). WAR for STAGEB(2u+6): its slot was
    // read in pair u-1, and all waves passed SBAR(u). RAW: each wave waited VM before SBAR.
    #pragma unroll 1
    for (int u = 0; u < 8; ++u) {
        if (u < 6)       { WAIT_VM(8); }
        else if (u == 6) { WAIT_VM(4); }
        else             { WAIT_VM(0); }
        SBAR;
        if (u < 5) { STAGEB(2 * u + 6); STAGEB(2 * u + 7); }
        TILE(2 * u);
        TILE(2 * u + 1);
        if (u == 3) FLUSH(0);                 // first 256-col half done (tiles 0-7)
        if (u == 7) FLUSH(1);                 // second half
    }
#undef STAGE_AHALF
#undef STAGEB
#undef READA
#undef TILE
#undef FLUSH
}

// ---------- fixup: global top-4 of 64 keys -> exact f32 -> argmax + gather ----------
__global__ void k_fixup(const unsigned* pk,  // == (u32*)d_out, intentionally no restrict
                        const float* __restrict__ x, const float* __restrict__ e,
                        float* out) {
    const int row = blockIdx.x * 4 + (threadIdx.x >> 6);
    const int t   = threadIdx.x & 63;   // t<32: half-split partial holder (256 cols each)
    unsigned long long kk0 = 0ull, kk1 = 0ull;
    if (t < 32) {
        const uint2 kv = reinterpret_cast<const uint2*>(pk + (size_t)row * 256)[t];
        const int col0 = t * 256 + 255 - (int)(kv.x & 255u);
        kk0 = ((unsigned long long)(kv.x & 0xFFFFFF00u) << 32) | (unsigned)(~col0);
        const int col1 = t * 256 + 255 - (int)(kv.y & 255u);
        kk1 = ((unsigned long long)(kv.y & 0xFFFFFF00u) << 32) | (unsigned)(~col1);
    }

    int cand[4];
    #pragma unroll
    for (int p = 0; p < 4; ++p) {
        unsigned long long m = kk0 > kk1 ? kk0 : kk1;
        #pragma unroll
        for (int off = 1; off < 64; off <<= 1) {
            const unsigned long long o = __shfl_xor(m, off);
            if (o > m) m = o;
        }
        cand[p] = (int)(~(unsigned)m) & (CCNT - 1);
        if (kk0 == m) kk0 = 0ull;
        if (kk1 == m) kk1 = 0ull;
    }

    const float4 xv = *reinterpret_cast<const float4*>(x + (size_t)row * DDIM + t * 4);
    float best = -INFINITY; int bc = 0x7fffffff;
    #pragma unroll
    for (int p = 0; p < 4; ++p) {
        const int c = cand[p];
        const float4 ev = *reinterpret_cast<const float4*>(e + (size_t)c * DDIM + t * 4);
        float d  = xv.x * ev.x + xv.y * ev.y + xv.z * ev.z + xv.w * ev.w;
        float ss = ev.x * ev.x + ev.y * ev.y + ev.z * ev.z + ev.w * ev.w;
        #pragma unroll
        for (int off = 1; off < 64; off <<= 1) {
            d  += __shfl_xor(d, off);
            ss += __shfl_xor(ss, off);
        }
        const float v = d * (1.0f / fmaxf(sqrtf(ss), 1e-12f));
        if (v > best || (v == best && c < bc)) { best = v; bc = c; }
    }

    if (t == 0) out[(size_t)QROWS * DDIM + row] = (float)bc;
    const float4 q = *reinterpret_cast<const float4*>(e + (size_t)bc * DDIM + t * 4);
    *reinterpret_cast<float4*>(out + (size_t)row * DDIM + t * 4) = q; // overwrites this row's partials only
}

extern "C" void kernel_launch(void* const* d_in, const int* in_sizes, int n_in,
                              void* d_out, int out_size, void* d_ws, size_t ws_size,
                              hipStream_t stream) {
    const float* x = (const float*)d_in[0];
    const float* e = (const float*)d_in[1];
    float* out = (float*)d_out;
    char* ws = (char*)d_ws;

    unsigned short* xb = (unsigned short*)ws;                             // 4 MB
    unsigned short* eb = (unsigned short*)(ws + (size_t)4 * 1024 * 1024); // 4 MB

    hipFuncSetAttribute(reinterpret_cast<const void*>(k_gemm),
                        hipFuncAttributeMaxDynamicSharedMemorySize, 131072);

    k_prep<<<3072, 256, 0, stream>>>(x, xb, e, eb);
    k_gemm<<<256, 512, 131072, stream>>>(xb, eb, (unsigned*)d_out);
    k_fixup<<<QROWS / 4, 256, 0, stream>>>((const unsigned*)d_out, x, e, out);
}